// Round 8
// baseline (846.502 us; speedup 1.0000x reference)
//
#include <hip/hip_runtime.h>

#define NBUS 118
#define BATCH 4096
#define NN (BATCH * NBUS)          // 483328 nodes
#define END_E (4 * NN)             // 1933312 no-diag edges
#define EF_E (END_E + NN)          // 2416640 full edges
#define NLAYERS 10

#define SPAN 472                   // fine dst bucket span = 4*NBUS (batch-aligned)
#define NFB 1024                   // 1024*472 == NN exactly
#define CSPAN 1888                 // coarse span = 4*SPAN; 256*1888 == NN exactly
#define NCB 256                    // coarse buckets
#define TILE 4096                  // edges per binA block
#define ND_TILES (END_E / TILE)    // 472 (exact)
#define F_TILES  (EF_E / TILE)     // 590 (exact)
#define CAPC_ND 8192               // coarse cap: mean 7552
#define CAPC_F  10240              // coarse cap: mean 9440
#define CAP_ND 2304                // fine cap: mean 1888 (even -> uint4-aligned)
#define CAP_F  2816                // fine cap: mean 2360 (even -> uint4-aligned)

#define NERR 64                    // spread error-atomic slots (stride 16 floats = 64B)

typedef unsigned int v4u __attribute__((ext_vector_type(4)));
__device__ __forceinline__ v4u ntl4u(const v4u* p) { return __builtin_nontemporal_load(p); }
__device__ __forceinline__ float wf(unsigned bits) { return __int_as_float((int)bits); }

// ---------- K1: p, denomInv, coarse cursors, err partials ----------
__global__ void init_kernel(const float* __restrict__ x,
                            const float* __restrict__ ybus,
                            float* __restrict__ p,
                            float* __restrict__ denomInv,
                            int* __restrict__ cursorC_nd,
                            int* __restrict__ cursorC_f,
                            float* __restrict__ errPartial) {
    int tid = blockIdx.x * blockDim.x + threadIdx.x;
    int stride = gridDim.x * blockDim.x;
    for (int i = tid; i < NN; i += stride) {
        float2 xi = ((const float2*)x)[i];
        p[i] = xi.x - xi.y;
        int b = i / NBUS;
        int j = i - b * NBUS;
        denomInv[i] = 1.0f / (ybus[b * (NBUS * NBUS) + j * (NBUS + 1)] * 100.0f);
    }
    for (int i = tid; i < (NLAYERS + 1) * NERR * 16; i += stride) errPartial[i] = 0.0f;
    if (tid < NCB) {
        cursorC_nd[tid] = tid * CAPC_ND;
        cursorC_f[tid]  = tid * CAPC_F;
    }
}

// ---------- K2 (binA): tile -> LDS bin by COARSE bucket (span 1888) -> staging ----------
// staged entry: .x = src | (dlCoarse<<19)  (src < 2^19, dl < 1888 = 11 bits), .y = bits(w*100)
__global__ __launch_bounds__(256) void binA_kernel(
        const int* __restrict__ src_nd, const int* __restrict__ dst_nd,
        const float* __restrict__ ea_nd,
        const int* __restrict__ src_f, const int* __restrict__ dst_f,
        const float* __restrict__ ea_f,
        int* __restrict__ cursorC_nd, int* __restrict__ cursorC_f,
        uint2* __restrict__ stgC_nd, uint2* __restrict__ stgC_f) {
    __shared__ uint2 buf[TILE];            // 32 KB
    __shared__ unsigned char sb[TILE];     // 4 KB
    __shared__ int hist[256];
    __shared__ int scanA[256];
    __shared__ int segStart[256];
    __shared__ int segGBase[256];

    bool isF = blockIdx.x >= ND_TILES;
    int tile = isF ? (blockIdx.x - ND_TILES) : blockIdx.x;
    const int* src = isF ? src_f : src_nd;
    const int* dst = isF ? dst_f : dst_nd;
    const float* ea = isF ? ea_f : ea_nd;
    int* cursor = isF ? cursorC_f : cursorC_nd;
    uint2* stg = isF ? stgC_f : stgC_nd;
    int cap = isF ? CAPC_F : CAPC_ND;

    int tid = threadIdx.x;
    int base = tile * TILE;

    hist[tid] = 0;
    __syncthreads();

    #pragma unroll
    for (int k = 0; k < TILE / 256; ++k) {
        unsigned d = (unsigned)dst[base + k * 256 + tid];
        atomicAdd(&hist[d / CSPAN], 1);
    }
    __syncthreads();

    int cnt = hist[tid];
    scanA[tid] = cnt;
    __syncthreads();
    for (int off = 1; off < 256; off <<= 1) {
        int t = (tid >= off) ? scanA[tid - off] : 0;
        __syncthreads();
        scanA[tid] += t;
        __syncthreads();
    }
    int excl = scanA[tid] - cnt;
    segStart[tid] = excl;
    hist[tid] = excl;
    if (cnt > 0) segGBase[tid] = atomicAdd(&cursor[tid], cnt);
    __syncthreads();

    #pragma unroll
    for (int k = 0; k < TILE / 256; ++k) {
        int e = base + k * 256 + tid;
        unsigned d = (unsigned)dst[e];
        unsigned bkt = d / CSPAN;
        int pos = atomicAdd(&hist[bkt], 1);
        unsigned dl = d - bkt * CSPAN;             // 11 bits
        buf[pos] = make_uint2((unsigned)src[e] | (dl << 19),
                              (unsigned)__float_as_int(ea[e] * 100.0f));
        sb[pos] = (unsigned char)bkt;
    }
    __syncthreads();

    #pragma unroll
    for (int k = 0; k < TILE / 256; ++k) {
        int slot = k * 256 + tid;
        int bkt = sb[slot];
        int gpos = segGBase[bkt] + (slot - segStart[bkt]);
        if (gpos < (bkt + 1) * cap)  // freak-overflow guard
            stg[gpos] = buf[slot];
    }
}

// ---------- K3 (binC): split coarse bucket -> 4 fine buckets (uint4 stream) ----------
// Reads coarse staging as uint4 (2 edges/lane/instr). Wave-aggregated fine
// cursors. Pads each fine bucket to an EVEN edge count with a (0,0) sentinel
// so the layer can read exact uint4s (sentinel: src=0, w=0 -> harmless).
__global__ __launch_bounds__(512) void binC_kernel(
        const uint2* __restrict__ stgC_nd, const uint2* __restrict__ stgC_f,
        const int* __restrict__ cursorC_nd, const int* __restrict__ cursorC_f,
        uint2* __restrict__ stg_nd, uint2* __restrict__ stg_f,
        int* __restrict__ cursor_nd, int* __restrict__ cursor_f) {
    __shared__ int lcur[4];
    bool isF = blockIdx.x >= NCB;
    int cb = isF ? (blockIdx.x - NCB) : blockIdx.x;
    int capC = isF ? CAPC_F : CAPC_ND;
    int capFine = isF ? CAP_F : CAP_ND;
    const uint2* in = (isF ? stgC_f : stgC_nd) + (long)cb * capC;
    const v4u* in4 = (const v4u*)in;
    uint2* out = isF ? stg_f : stg_nd;
    int* curOut = isF ? cursor_f : cursor_nd;
    int tot = (isF ? cursorC_f[cb] : cursorC_nd[cb]) - cb * capC;
    if (tot > capC) tot = capC;
    int tot4 = (tot + 1) >> 1;

    int tid = threadIdx.x;
    int lane = tid & 63;
    if (tid < 4) lcur[tid] = 0;
    __syncthreads();

    for (int i4 = tid; i4 < tot4; i4 += 512) {
        v4u v = ntl4u(in4 + i4);
        #pragma unroll
        for (int h = 0; h < 2; ++h) {
            unsigned px = h ? v.z : v.x;
            unsigned py = h ? v.w : v.y;
            bool act = (h == 0) || (2 * i4 + 1 < tot);
            unsigned dl11 = px >> 19;
            int f = (dl11 >= 3 * SPAN) ? 3 : (dl11 >= 2 * SPAN) ? 2
                    : (dl11 >= SPAN) ? 1 : 0;
            unsigned dl9 = dl11 - (unsigned)f * SPAN;
            unsigned long long m0 = __ballot(act && f == 0);
            unsigned long long m1 = __ballot(act && f == 1);
            unsigned long long m2 = __ballot(act && f == 2);
            unsigned long long m3 = __ballot(act && f == 3);
            unsigned long long mf = (f == 0) ? m0 : (f == 1) ? m1 : (f == 2) ? m2 : m3;
            int leader = mf ? (__ffsll(mf) - 1) : 0;
            int base = 0;
            if (act && lane == leader) base = atomicAdd(&lcur[f], (int)__popcll(mf));
            base = __shfl(base, leader, 64);   // all lanes execute (leader active)
            if (act) {
                int rank = __popcll(mf & ((1ull << lane) - 1ull));
                int pos = base + rank;
                if (pos < capFine)
                    out[(long)(cb * 4 + f) * capFine + pos] =
                        make_uint2((px & 0x7FFFFu) | (dl9 << 19), py);
            }
        }
    }
    __syncthreads();
    if (tid < 4) {
        int fbG = cb * 4 + tid;
        int c = lcur[tid] < capFine ? lcur[tid] : capFine;
        if (c & 1) {                            // pad to even for uint4 layer reads
            out[(long)fbG * capFine + c] = make_uint2(0u, 0u);
            ++c;                                 // odd c < even capFine -> c+1 <= capFine
        }
        curOut[fbG] = fbG * capFine + c;
    }
}

// ---------- K4: layer 0 (theta = 0): out0 = p*denomInv - slack ----------
__global__ void out0_kernel(const float* __restrict__ p,
                            const float* __restrict__ denomInv,
                            float* __restrict__ out) {
    int b = blockIdx.x;
    int j = threadIdx.x;
    int i = b * NBUS + j;
    __shared__ float z0;
    float z = 0.0f;
    if (j < NBUS) z = p[i] * denomInv[i];
    if (j == 0) z0 = z;
    __syncthreads();
    if (j < NBUS) out[i] = z - z0;
}

// ---------- K5: edge-parallel fused layer, uint4 nontemporal staged loads ----------
// Block = one 472-node bucket. Staged edges are even-padded -> exact uint4
// reads: 3 nt loads per side (6 edges each). Gathers stay cached (L2 holds
// cur); out written nontemporal. LDS atomics accumulate; slack fused.
template <bool DO_OUT>
__global__ __launch_bounds__(512) void layer_kernel(
        const uint2* __restrict__ stg_nd, const uint2* __restrict__ stg_f,
        const int* __restrict__ cursor_nd, const int* __restrict__ cursor_f,
        const float* __restrict__ p, const float* __restrict__ denomInv,
        const float* __restrict__ cur,
        float* __restrict__ out,
        float* __restrict__ errPart /* NERR slots, stride 16 */) {
    __shared__ float zF[SPAN];
    __shared__ float zN[SPAN];
    __shared__ float ws[8];
    int tid = threadIdx.x;
    int fb = blockIdx.x;
    int gbase = fb * SPAN;

    if (tid < SPAN) { zF[tid] = 0.0f; zN[tid] = 0.0f; }
    __syncthreads();

    int totF = cursor_f[fb] - fb * CAP_F;   if (totF > CAP_F) totF = CAP_F;
    int nF4 = totF >> 1;                    // even-padded by binC
    const v4u* sgF4 = (const v4u*)(stg_f + (long)fb * CAP_F);
    int nN4 = 0;
    const v4u* sgN4 = (const v4u*)(stg_nd + (long)fb * CAP_ND);
    if (DO_OUT) {
        int totN = cursor_nd[fb] - fb * CAP_ND; if (totN > CAP_ND) totN = CAP_ND;
        nN4 = totN >> 1;
    }

    // --- phase A: nt uint4 loads (2 edges each), sentinel-padded ---
    const v4u zz = {0u, 0u, 0u, 0u};
    v4u f0 = (tid          < nF4) ? ntl4u(sgF4 + tid       ) : zz;
    v4u f1 = (tid +  512   < nF4) ? ntl4u(sgF4 + tid +  512) : zz;
    v4u f2 = (tid + 1024   < nF4) ? ntl4u(sgF4 + tid + 1024) : zz;
    v4u n0 = zz, n1 = zz, n2 = zz;
    if (DO_OUT) {
        n0 = (tid        < nN4) ? ntl4u(sgN4 + tid       ) : zz;
        n1 = (tid +  512 < nN4) ? ntl4u(sgN4 + tid +  512) : zz;
        n2 = (tid + 1024 < nN4) ? ntl4u(sgN4 + tid + 1024) : zz;
    }

    // --- phase B: issue all gathers (independent -> all in flight) ---
    float gf0 = cur[f0.x & 0x7FFFF], gf1 = cur[f0.z & 0x7FFFF];
    float gf2 = cur[f1.x & 0x7FFFF], gf3 = cur[f1.z & 0x7FFFF];
    float gf4 = cur[f2.x & 0x7FFFF], gf5 = cur[f2.z & 0x7FFFF];
    float gn0 = 0.0f, gn1 = 0.0f, gn2 = 0.0f, gn3 = 0.0f, gn4 = 0.0f, gn5 = 0.0f;
    if (DO_OUT) {
        gn0 = cur[n0.x & 0x7FFFF]; gn1 = cur[n0.z & 0x7FFFF];
        gn2 = cur[n1.x & 0x7FFFF]; gn3 = cur[n1.z & 0x7FFFF];
        gn4 = cur[n2.x & 0x7FFFF]; gn5 = cur[n2.z & 0x7FFFF];
    }

    // --- phase C: LDS atomic accumulate (sentinels add 0.0 to slot 0) ---
    atomicAdd(&zF[f0.x >> 19], gf0 * wf(f0.y));
    atomicAdd(&zF[f0.z >> 19], gf1 * wf(f0.w));
    atomicAdd(&zF[f1.x >> 19], gf2 * wf(f1.y));
    atomicAdd(&zF[f1.z >> 19], gf3 * wf(f1.w));
    atomicAdd(&zF[f2.x >> 19], gf4 * wf(f2.y));
    atomicAdd(&zF[f2.z >> 19], gf5 * wf(f2.w));
    if (DO_OUT) {
        atomicAdd(&zN[n0.x >> 19], gn0 * wf(n0.y));
        atomicAdd(&zN[n0.z >> 19], gn1 * wf(n0.w));
        atomicAdd(&zN[n1.x >> 19], gn2 * wf(n1.y));
        atomicAdd(&zN[n1.z >> 19], gn3 * wf(n1.w));
        atomicAdd(&zN[n2.x >> 19], gn4 * wf(n2.y));
        atomicAdd(&zN[n2.z >> 19], gn5 * wf(n2.w));
    }
    __syncthreads();

    // --- combine: err + z + fused slack ---
    float acc = 0.0f;
    if (tid < SPAN) {
        float pv = p[gbase + tid];
        acc = fabsf(pv - zF[tid]);
        if (DO_OUT) zN[tid] = (pv - zN[tid]) * denomInv[gbase + tid];
    }
    if (DO_OUT) {
        __syncthreads();
        if (tid < SPAN)
            __builtin_nontemporal_store(zN[tid] - zN[(tid / NBUS) * NBUS],
                                        &out[gbase + tid]);
    }
    for (int off = 32; off > 0; off >>= 1) acc += __shfl_down(acc, off, 64);
    if ((tid & 63) == 0) ws[tid >> 6] = acc;
    __syncthreads();
    if (tid == 0) {
        float t = 0.0f;
        #pragma unroll
        for (int w = 0; w < 8; ++w) t += ws[w];
        atomicAdd(&errPart[(fb & (NERR - 1)) * 16], t);
    }
}

// ---------- K6: reduce err partials -> errs[11] ----------
__global__ void err_reduce_kernel(const float* __restrict__ errPartial,
                                  float* __restrict__ errs) {
    int l = blockIdx.x;
    int t = threadIdx.x;  // 64
    float v = errPartial[l * (NERR * 16) + t * 16];
    for (int off = 32; off > 0; off >>= 1) v += __shfl_down(v, off, 64);
    if (t == 0) errs[l] = v;
}

extern "C" void kernel_launch(void* const* d_in, const int* in_sizes, int n_in,
                              void* d_out, int out_size, void* d_ws, size_t ws_size,
                              hipStream_t stream) {
    const float* x     = (const float*)d_in[0];
    const int*   ei_nd = (const int*)d_in[2];
    const float* ea_nd = (const float*)d_in[3];
    const int*   ei    = (const int*)d_in[4];
    const float* ea    = (const float*)d_in[5];
    const float* ybus  = (const float*)d_in[6];

    float* out_f = (float*)d_out;
    float* errs  = out_f + NN;

    // workspace carve (4-byte units; staged arrays stay 16B-aligned: even caps)
    float* wsf        = (float*)d_ws;
    float* p          = wsf;          wsf += NN;
    float* denomInv   = wsf;          wsf += NN;
    float* outA       = wsf;          wsf += NN;
    float* outB       = wsf;          wsf += NN;
    int*   cursorC_nd = (int*)wsf;    wsf += NCB;
    int*   cursorC_f  = (int*)wsf;    wsf += NCB;
    int*   cursor_nd  = (int*)wsf;    wsf += NFB;
    int*   cursor_f   = (int*)wsf;    wsf += NFB;
    float* errPartial = wsf;          wsf += (NLAYERS + 1) * NERR * 16;  // 11264
    uint2* stgC_nd    = (uint2*)wsf;  wsf += 2LL * NCB * CAPC_ND;
    uint2* stgC_f     = (uint2*)wsf;  wsf += 2LL * NCB * CAPC_F;
    uint2* stg_nd     = (uint2*)wsf;  wsf += 2LL * NFB * CAP_ND;
    uint2* stg_f      = (uint2*)wsf;  wsf += 2LL * NFB * CAP_F;

    const int* src_nd = ei_nd;
    const int* dst_nd = ei_nd + END_E;
    const int* src_f  = ei;
    const int* dst_f  = ei + EF_E;

    // ---- build phase ----
    init_kernel<<<2048, 256, 0, stream>>>(x, ybus, p, denomInv,
                                          cursorC_nd, cursorC_f, errPartial);
    binA_kernel<<<ND_TILES + F_TILES, 256, 0, stream>>>(
        src_nd, dst_nd, ea_nd, src_f, dst_f, ea,
        cursorC_nd, cursorC_f, stgC_nd, stgC_f);
    binC_kernel<<<2 * NCB, 512, 0, stream>>>(
        stgC_nd, stgC_f, cursorC_nd, cursorC_f,
        stg_nd, stg_f, cursor_nd, cursor_f);

    // ---- iterate phase ----
    out0_kernel<<<BATCH, 128, 0, stream>>>(p, denomInv, outA);
    const float* cur = outA;
    for (int k = 1; k <= NLAYERS; ++k) {
        float* nxt = (k == NLAYERS) ? out_f : ((k & 1) ? outB : outA);
        layer_kernel<true><<<NFB, 512, 0, stream>>>(
            stg_nd, stg_f, cursor_nd, cursor_f, p, denomInv, cur, nxt,
            errPartial + (long)(k - 1) * NERR * 16);
        cur = nxt;
    }
    layer_kernel<false><<<NFB, 512, 0, stream>>>(
        stg_nd, stg_f, cursor_nd, cursor_f, p, denomInv, cur, nullptr,
        errPartial + (long)NLAYERS * NERR * 16);
    err_reduce_kernel<<<NLAYERS + 1, 64, 0, stream>>>(errPartial, errs);
}